// Round 1
// baseline (134.024 us; speedup 1.0000x reference)
//
#include <hip/hip_runtime.h>

// Problem constants (from reference): B=128, L=1024, D=2048, f32 in/out.
constexpr int Bc = 128;
constexpr int Lc = 1024;
constexpr int Dc = 2048;

constexpr int THREADS   = 256;
constexpr int VEC       = 4;                   // float4 per thread
constexpr int DCOLS_BLK = THREADS * VEC;       // 1024 columns per block
constexpr int DBLKS     = Dc / DCOLS_BLK;      // 2
constexpr int LCHUNK    = 128;
constexpr int LCHUNKS   = Lc / LCHUNK;         // 8

__global__ __launch_bounds__(THREADS) void avg_pool_var_kernel(
    const float* __restrict__ feat,
    const int*   __restrict__ lengths,
    float*       __restrict__ out)
{
    // blockIdx.x encodes (b, dblk, lc)
    int bid  = blockIdx.x;
    int lc   = bid % LCHUNKS;
    int dblk = (bid / LCHUNKS) % DBLKS;
    int b    = bid / (LCHUNKS * DBLKS);

    int len = lengths[b];
    int eff = (len > 0) ? len : Lc;

    int l0 = lc * LCHUNK;
    int l1 = l0 + LCHUNK;
    if (l1 > eff) l1 = eff;
    if (l0 >= l1) return;                      // block-uniform early-out

    int col = dblk * DCOLS_BLK + (int)threadIdx.x * VEC;
    const float* p = feat + (size_t)b * Lc * Dc + (size_t)l0 * Dc + col;

    float ax = 0.f, ay = 0.f, az = 0.f, aw = 0.f;
    #pragma unroll 4
    for (int l = l0; l < l1; ++l, p += Dc) {
        float4 v = *reinterpret_cast<const float4*>(p);
        ax += v.x; ay += v.y; az += v.z; aw += v.w;
    }

    float inv = 1.0f / (float)eff;
    float* o = out + (size_t)b * Dc + col;
    atomicAdd(o + 0, ax * inv);
    atomicAdd(o + 1, ay * inv);
    atomicAdd(o + 2, az * inv);
    atomicAdd(o + 3, aw * inv);
}

extern "C" void kernel_launch(void* const* d_in, const int* in_sizes, int n_in,
                              void* d_out, int out_size, void* d_ws, size_t ws_size,
                              hipStream_t stream)
{
    const float* feat    = (const float*)d_in[0];
    const int*   lengths = (const int*)d_in[1];
    float*       out     = (float*)d_out;

    // Harness poisons d_out once and never re-poisons between replays:
    // zero it every call (graph-capture-safe memset node).
    hipMemsetAsync(out, 0, (size_t)out_size * sizeof(float), stream);

    dim3 grid(Bc * DBLKS * LCHUNKS);
    dim3 block(THREADS);
    avg_pool_var_kernel<<<grid, block, 0, stream>>>(feat, lengths, out);
}

// Round 3
// 102.675 us; speedup vs baseline: 1.3053x; 1.3053x over previous
//
#include <hip/hip_runtime.h>

// Problem constants (from reference): B=128, L=1024, D=2048, f32 in/out.
constexpr int Bc = 128;
constexpr int Lc = 1024;
constexpr int Dc = 2048;

constexpr int THREADS   = 256;
constexpr int VEC       = 4;                   // float4 per thread
constexpr int DCOLS_BLK = THREADS * VEC;       // 1024 columns per block
constexpr int DBLKS     = Dc / DCOLS_BLK;      // 2
constexpr int NL        = 8;                   // row-interleave groups

typedef float v4f __attribute__((ext_vector_type(4)));

__global__ __launch_bounds__(THREADS) void avg_pool_var_kernel(
    const float* __restrict__ feat,
    const int*   __restrict__ lengths,
    float*       __restrict__ out)
{
    // blockIdx.x encodes (b, dblk, lc); lc picks rows l ≡ lc (mod NL)
    int bid  = blockIdx.x;
    int lc   = bid % NL;
    int dblk = (bid / NL) % DBLKS;
    int b    = bid / (NL * DBLKS);

    int len = lengths[b];
    int eff = (len > 0) ? len : Lc;

    int col = dblk * DCOLS_BLK + (int)threadIdx.x * VEC;
    const float* p = feat + (size_t)b * Lc * Dc + (size_t)lc * Dc + col;

    float ax = 0.f, ay = 0.f, az = 0.f, aw = 0.f;
    #pragma unroll 4
    for (int l = lc; l < eff; l += NL, p += (size_t)NL * Dc) {
        v4f v = __builtin_nontemporal_load(reinterpret_cast<const v4f*>(p));
        ax += v.x; ay += v.y; az += v.z; aw += v.w;
    }

    float inv = 1.0f / (float)eff;
    float* o = out + (size_t)b * Dc + col;
    atomicAdd(o + 0, ax * inv);
    atomicAdd(o + 1, ay * inv);
    atomicAdd(o + 2, az * inv);
    atomicAdd(o + 3, aw * inv);
}

extern "C" void kernel_launch(void* const* d_in, const int* in_sizes, int n_in,
                              void* d_out, int out_size, void* d_ws, size_t ws_size,
                              hipStream_t stream)
{
    const float* feat    = (const float*)d_in[0];
    const int*   lengths = (const int*)d_in[1];
    float*       out     = (float*)d_out;

    // Harness poisons d_out once and never re-poisons between replays:
    // zero it every call (graph-capture-safe memset node).
    (void)hipMemsetAsync(out, 0, (size_t)out_size * sizeof(float), stream);

    dim3 grid(Bc * DBLKS * NL);
    dim3 block(THREADS);
    avg_pool_var_kernel<<<grid, block, 0, stream>>>(feat, lengths, out);
}